// Round 3
// baseline (360.988 us; speedup 1.0000x reference)
//
#include <hip/hip_runtime.h>
#include <stdint.h>

#define N_NODES 6144
#define LOG2E 1.44269504088896f

typedef float f32x4 __attribute__((ext_vector_type(4)));
typedef short short8 __attribute__((ext_vector_type(8)));

extern "C" __device__ float __ocml_native_exp2_f32(float);

// pack two floats -> two bf16 (round-half-up) in one u32: lo=a, hi=b
__device__ __forceinline__ unsigned int pack2bf(float a, float b) {
  unsigned int ua = __float_as_uint(a) + 0x8000u;
  unsigned int ub = __float_as_uint(b) + 0x8000u;
  return __builtin_amdgcn_perm(ub, ua, 0x07060302u);
}

// K1: h = x*W (fp32). hfT (bf16 [c][n]) written coalesced via LDS transpose.
// s_src2/s_dst2 = (h . a_{src,dst}) * log2(e), reduced via LDS partials.
// 96 blocks x 256 thr; block = 64 nodes x all 128 channels.
__global__ __launch_bounds__(256) void k1_feat(const float* __restrict__ x,
                                               const float* __restrict__ W,
                                               const float* __restrict__ a,
                                               unsigned short* __restrict__ hfT,
                                               float* __restrict__ s_src2,
                                               float* __restrict__ s_dst2) {
  __shared__ float xl[64][132];   // 33.8 KB (pad 132: stride-128 reads conflict-free)
  __shared__ float Wl[64][128];   // 32 KB
  int t = threadIdx.x;
  int n0 = blockIdx.x * 64;
  // stage x tile (64 x 128)
  for (int u = t; u < 2048; u += 256) {
    int row = u >> 5, c4 = (u & 31) << 2;
    *(float4*)&xl[row][c4] = *(const float4*)(x + (size_t)(n0 + row) * 128 + c4);
  }
  int cg = t & 31, c0 = cg << 2;   // 4 channels per thread
  int ng = t >> 5, nb = ng << 3;   // 8 nodes per thread
  float acc[8][4] = {};
  for (int ic = 0; ic < 2; ++ic) {
    __syncthreads();
    for (int u = t; u < 2048; u += 256) {
      int ii = u >> 5, c4 = (u & 31) << 2;
      int hh = c4 >> 5, d0 = c4 & 31;
      *(float4*)&Wl[ii][c4] = *(const float4*)(W + hh * 4096 + (ic * 64 + ii) * 32 + d0);
    }
    __syncthreads();
    #pragma unroll 4
    for (int ii = 0; ii < 64; ++ii) {
      float4 wv = *(float4*)&Wl[ii][c0];
      int i = ic * 64 + ii;
      #pragma unroll
      for (int r = 0; r < 8; ++r) {
        float xv = xl[nb + r][i];
        acc[r][0] += xv * wv.x; acc[r][1] += xv * wv.y;
        acc[r][2] += xv * wv.z; acc[r][3] += xv * wv.w;
      }
    }
  }
  __syncthreads();
  // overlay LDS: tb = bf16 [128][66] in xl region; pb = float [2][64][33] in Wl region
  unsigned short* tb = (unsigned short*)&xl[0][0];
  float* pb = &Wl[0][0];
  int hh = c0 >> 5, d0 = c0 & 31;
  float4 adv = *(const float4*)(a + hh * 64 + d0);        // a_dst
  float4 asv = *(const float4*)(a + hh * 64 + 32 + d0);   // a_src
  #pragma unroll
  for (int cc = 0; cc < 4; ++cc) {
    unsigned int* dst = (unsigned int*)(tb + (c0 + cc) * 66 + nb);
    #pragma unroll
    for (int p = 0; p < 4; ++p)
      dst[p] = pack2bf(acc[2 * p][cc], acc[2 * p + 1][cc]);
  }
  #pragma unroll
  for (int r = 0; r < 8; ++r) {
    float pd = acc[r][0] * adv.x + acc[r][1] * adv.y + acc[r][2] * adv.z + acc[r][3] * adv.w;
    float ps = acc[r][0] * asv.x + acc[r][1] * asv.y + acc[r][2] * asv.z + acc[r][3] * asv.w;
    pb[(nb + r) * 33 + cg] = pd;
    pb[2112 + (nb + r) * 33 + cg] = ps;
  }
  __syncthreads();
  // coalesced hfT store: thread -> (row=c, half), 64 B each
  {
    int row = t >> 1, half = t & 1;
    const unsigned int* s32 = (const unsigned int*)(tb + row * 66 + half * 32);
    unsigned int v[16];
    #pragma unroll
    for (int q = 0; q < 16; ++q) v[q] = s32[q];
    unsigned short* gdst = hfT + (size_t)row * N_NODES + n0 + half * 32;
    #pragma unroll
    for (int q = 0; q < 4; ++q) {
      uint4 w4; w4.x = v[4 * q]; w4.y = v[4 * q + 1]; w4.z = v[4 * q + 2]; w4.w = v[4 * q + 3];
      *(uint4*)(gdst + q * 8) = w4;
    }
  }
  // s reduction: task = (n, h, dst/src); sum 8 channel-group partials
  for (int task = t; task < 512; task += 256) {
    int n = task & 63, hz = task >> 6;
    int h = hz & 3, sdx = hz >> 2;
    const float* src = pb + sdx * 2112 + n * 33 + h * 8;
    float s = src[0] + src[1] + src[2] + src[3] + src[4] + src[5] + src[6] + src[7];
    float* out = sdx ? s_src2 : s_dst2;
    out[h * N_NODES + n0 + n] = s * LOG2E;
  }
}

// K2: fused masked-softmax attention aggregate.
// Block = 4 waves = 4 heads, 16-row m-tile, k-slice 1536 (split 4).
// s_dst2 staged in LDS (broadcast); adj/hfT loads register-prefetched depth 1.
// Weights built per-lane in MFMA A-layout; Z via ones-B MFMA.
__global__ __launch_bounds__(256) void k2_attn(const int* __restrict__ adj,
                                               const unsigned short* __restrict__ hfT,
                                               const float* __restrict__ s_src2,
                                               const float* __restrict__ s_dst2,
                                               float* __restrict__ Zpart,
                                               float* __restrict__ part) {
  __shared__ float sd[4][1536];   // 24 KB
  int t = threadIdx.x;
  int h = t >> 6, lane = t & 63, m = lane & 15, quad = lane >> 4;
  int bx = blockIdx.x;
  int slice = bx & 3, mt = bx >> 2;
  int i0 = mt << 4, kbase = slice * 1536;
  {
    const float4* g = (const float4*)s_dst2;
    float4* l = (float4*)sd;
    int kb4 = kbase >> 2;
    #pragma unroll
    for (int hx = 0; hx < 4; ++hx)
      for (int u = t; u < 384; u += 256)
        l[hx * 384 + u] = g[hx * 1536 + kb4 + u];
  }
  float ssrc2 = s_src2[h * N_NODES + i0 + m];
  __syncthreads();

  const int* arow = adj + (size_t)(i0 + m) * N_NODES + kbase + (quad << 3);
  const unsigned short* hp0 = hfT + (size_t)(h * 32 + m) * N_NODES + kbase + (quad << 3);
  const unsigned short* hp1 = hp0 + (size_t)16 * N_NODES;
  f32x4 acc0 = {0.f, 0.f, 0.f, 0.f}, acc1 = {0.f, 0.f, 0.f, 0.f};
  f32x4 accz = {0.f, 0.f, 0.f, 0.f};
  union { unsigned int u[4]; short8 v; } ones;
  #pragma unroll
  for (int q = 0; q < 4; ++q) ones.u[q] = 0x3F803F80u;

  int4 A0 = *(const int4*)arow;
  int4 A1 = *(const int4*)(arow + 4);
  int4 B0 = *(const int4*)hp0;
  int4 B1 = *(const int4*)hp1;

  #pragma unroll 2
  for (int it = 0; it < 48; ++it) {
    int4 nA0, nA1, nB0, nB1;
    bool pf = it < 47;
    if (pf) {
      int kk = (it + 1) << 5;
      nA0 = *(const int4*)(arow + kk);
      nA1 = *(const int4*)(arow + kk + 4);
      nB0 = *(const int4*)(hp0 + kk);
      nB1 = *(const int4*)(hp1 + kk);
    }
    int base = (it << 5) + (quad << 3);
    f32x4 d0 = *(f32x4*)&sd[h][base];
    f32x4 d1 = *(f32x4*)&sd[h][base + 4];
    float dv[8] = {d0[0], d0[1], d0[2], d0[3], d1[0], d1[1], d1[2], d1[3]};
    int av[8] = {A0.x, A0.y, A0.z, A0.w, A1.x, A1.y, A1.z, A1.w};
    float w[8];
    #pragma unroll
    for (int j = 0; j < 8; ++j) {
      float e = ssrc2 + dv[j];                 // (s_src+s_dst) * log2e
      float lr = fmaxf(e, 0.2f * e);           // leaky-relu, log2 domain
      float ex = __ocml_native_exp2_f32(lr);   // v_exp_f32
      w[j] = (av[j] > 0) ? ex : 0.f;
    }
    union { unsigned int u[4]; short8 v; } afr;
    #pragma unroll
    for (int j = 0; j < 4; ++j) afr.u[j] = pack2bf(w[2 * j], w[2 * j + 1]);
    union { int4 i; short8 v; } b0, b1;
    b0.i = B0; b1.i = B1;
    acc0 = __builtin_amdgcn_mfma_f32_16x16x32_bf16(afr.v, b0.v, acc0, 0, 0, 0);
    acc1 = __builtin_amdgcn_mfma_f32_16x16x32_bf16(afr.v, b1.v, acc1, 0, 0, 0);
    accz = __builtin_amdgcn_mfma_f32_16x16x32_bf16(afr.v, ones.v, accz, 0, 0, 0);
    if (pf) { A0 = nA0; A1 = nA1; B0 = nB0; B1 = nB1; }
  }
  if (m == 0) {
    #pragma unroll
    for (int r = 0; r < 4; ++r)
      Zpart[(size_t)(slice * 4 + h) * N_NODES + i0 + (quad << 2) + r] = accz[r];
  }
  float* pb = part + (size_t)slice * (N_NODES * 128) + h * (N_NODES * 32) +
              (size_t)i0 * 32;
  #pragma unroll
  for (int r = 0; r < 4; ++r) {
    int row = (quad << 2) + r;  // D layout: col=lane&15, row=quad*4+reg
    pb[row * 32 + m] = acc0[r];
    pb[row * 32 + 16 + m] = acc1[r];
  }
}

// K3: out = sum_s part[s] / sum_s Z[s]
__global__ __launch_bounds__(256) void k3_final(const float* __restrict__ part,
                                                const float* __restrict__ Zpart,
                                                float* __restrict__ out) {
  unsigned int idx4 = blockIdx.x * 256 + threadIdx.x;
  unsigned int h = idx4 / 49152u;
  unsigned int i = (idx4 - h * 49152u) >> 3;
  float z = 0.f;
  #pragma unroll
  for (int s = 0; s < 4; ++s) z += Zpart[(s * 4 + h) * N_NODES + i];
  f32x4 p = {0.f, 0.f, 0.f, 0.f};
  const f32x4* P = (const f32x4*)part;
  #pragma unroll
  for (int s = 0; s < 4; ++s) p += P[(size_t)s * 196608u + idx4];
  float rz = 1.0f / z;
  ((f32x4*)out)[idx4] = p * rz;
}

extern "C" void kernel_launch(void* const* d_in, const int* in_sizes, int n_in,
                              void* d_out, int out_size, void* d_ws, size_t ws_size,
                              hipStream_t stream) {
  const float* x = (const float*)d_in[0];
  const int* adj = (const int*)d_in[1];
  const float* W = (const float*)d_in[2];
  const float* a = (const float*)d_in[3];
  float* out = (float*)d_out;

  float* wsf = (float*)d_ws;
  unsigned short* hfT = (unsigned short*)wsf;   // 128*6144 bf16
  float* s_src2 = wsf + 393216;
  float* s_dst2 = s_src2 + 24576;
  float* Zpart  = s_dst2 + 24576;               // 4 slices * 4*6144
  float* part   = Zpart + 98304;                // 4 slices * 786432

  hipLaunchKernelGGL(k1_feat, dim3(96), dim3(256), 0, stream, x, W, a, hfT, s_src2, s_dst2);
  hipLaunchKernelGGL(k2_attn, dim3(1536), dim3(256), 0, stream, adj, hfT, s_src2, s_dst2,
                     Zpart, part);
  hipLaunchKernelGGL(k3_final, dim3(768), dim3(256), 0, stream, part, Zpart, out);
}

// Round 4
// 348.889 us; speedup vs baseline: 1.0347x; 1.0347x over previous
//
#include <hip/hip_runtime.h>
#include <stdint.h>

#define N_NODES 6144
#define LOG2E 1.44269504088896f

typedef float f32x4 __attribute__((ext_vector_type(4)));
typedef short short8 __attribute__((ext_vector_type(8)));
typedef unsigned int uint32;

extern "C" __device__ float __ocml_native_exp2_f32(float);

// pack two floats -> two bf16 (round-half-up) in one u32: lo=a, hi=b
__device__ __forceinline__ unsigned int pack2bf(float a, float b) {
  unsigned int ua = __float_as_uint(a) + 0x8000u;
  unsigned int ub = __float_as_uint(b) + 0x8000u;
  return __builtin_amdgcn_perm(ub, ua, 0x07060302u);
}

// K0: bit-pack adjacency. Row i, bit k (little-endian u64 words). 151MB -> 4.7MB.
__global__ __launch_bounds__(256) void k0_pack(const int* __restrict__ adj,
                                               unsigned long long* __restrict__ maskbuf) {
  int t = threadIdx.x;
  int wid = t >> 6, lane = t & 63;
  int row = blockIdx.x * 4 + wid;
  const int* ar = adj + (size_t)row * N_NODES + lane;
  unsigned long long* mr = maskbuf + (size_t)row * 96;
  #pragma unroll 4
  for (int c = 0; c < 96; ++c) {
    int v = ar[c * 64];
    unsigned long long b = __ballot(v > 0);
    if (lane == 0) mr[c] = b;
  }
}

// K1: h = x*W (fp32). hfT (bf16 [c][n]) coalesced via LDS transpose;
// s_src2/s_dst2 = (h . a_{src,dst}) * log2(e).
__global__ __launch_bounds__(256) void k1_feat(const float* __restrict__ x,
                                               const float* __restrict__ W,
                                               const float* __restrict__ a,
                                               unsigned short* __restrict__ hfT,
                                               float* __restrict__ s_src2,
                                               float* __restrict__ s_dst2) {
  __shared__ float xl[64][132];
  __shared__ float Wl[64][128];
  int t = threadIdx.x;
  int n0 = blockIdx.x * 64;
  for (int u = t; u < 2048; u += 256) {
    int row = u >> 5, c4 = (u & 31) << 2;
    *(float4*)&xl[row][c4] = *(const float4*)(x + (size_t)(n0 + row) * 128 + c4);
  }
  int cg = t & 31, c0 = cg << 2;
  int ng = t >> 5, nb = ng << 3;
  float acc[8][4] = {};
  for (int ic = 0; ic < 2; ++ic) {
    __syncthreads();
    for (int u = t; u < 2048; u += 256) {
      int ii = u >> 5, c4 = (u & 31) << 2;
      int hh = c4 >> 5, d0 = c4 & 31;
      *(float4*)&Wl[ii][c4] = *(const float4*)(W + hh * 4096 + (ic * 64 + ii) * 32 + d0);
    }
    __syncthreads();
    #pragma unroll 4
    for (int ii = 0; ii < 64; ++ii) {
      float4 wv = *(float4*)&Wl[ii][c0];
      int i = ic * 64 + ii;
      #pragma unroll
      for (int r = 0; r < 8; ++r) {
        float xv = xl[nb + r][i];
        acc[r][0] += xv * wv.x; acc[r][1] += xv * wv.y;
        acc[r][2] += xv * wv.z; acc[r][3] += xv * wv.w;
      }
    }
  }
  __syncthreads();
  unsigned short* tb = (unsigned short*)&xl[0][0];   // bf16 [128][66]
  float* pb = &Wl[0][0];                             // float [2][64][33]
  int hh = c0 >> 5, d0 = c0 & 31;
  float4 adv = *(const float4*)(a + hh * 64 + d0);
  float4 asv = *(const float4*)(a + hh * 64 + 32 + d0);
  #pragma unroll
  for (int cc = 0; cc < 4; ++cc) {
    unsigned int* dst = (unsigned int*)(tb + (c0 + cc) * 66 + nb);
    #pragma unroll
    for (int p = 0; p < 4; ++p)
      dst[p] = pack2bf(acc[2 * p][cc], acc[2 * p + 1][cc]);
  }
  #pragma unroll
  for (int r = 0; r < 8; ++r) {
    float pd = acc[r][0] * adv.x + acc[r][1] * adv.y + acc[r][2] * adv.z + acc[r][3] * adv.w;
    float ps = acc[r][0] * asv.x + acc[r][1] * asv.y + acc[r][2] * asv.z + acc[r][3] * asv.w;
    pb[(nb + r) * 33 + cg] = pd;
    pb[2112 + (nb + r) * 33 + cg] = ps;
  }
  __syncthreads();
  {
    int row = t >> 1, half = t & 1;
    const unsigned int* s32 = (const unsigned int*)(tb + row * 66 + half * 32);
    unsigned int v[16];
    #pragma unroll
    for (int q = 0; q < 16; ++q) v[q] = s32[q];
    unsigned short* gdst = hfT + (size_t)row * N_NODES + n0 + half * 32;
    #pragma unroll
    for (int q = 0; q < 4; ++q) {
      uint4 w4; w4.x = v[4 * q]; w4.y = v[4 * q + 1]; w4.z = v[4 * q + 2]; w4.w = v[4 * q + 3];
      *(uint4*)(gdst + q * 8) = w4;
    }
  }
  for (int task = t; task < 512; task += 256) {
    int n = task & 63, hz = task >> 6;
    int h = hz & 3, sdx = hz >> 2;
    const float* src = pb + sdx * 2112 + n * 33 + h * 8;
    float s = src[0] + src[1] + src[2] + src[3] + src[4] + src[5] + src[6] + src[7];
    float* out = sdx ? s_src2 : s_dst2;
    out[h * N_NODES + n0 + n] = s * LOG2E;
  }
}

// K2: fused masked-softmax aggregate. Block = 4 waves = 4 heads, 16-row m-tile,
// k-slice 1536 (split 4). adj as bitmask (L2-resident), hfT ping-pong prefetch,
// s_dst2 in LDS. Weights built in MFMA A-layout; Z via ones-B MFMA.
__global__ __launch_bounds__(256, 4) void k2_attn(const uint32* __restrict__ maskw,
                                                  const unsigned short* __restrict__ hfT,
                                                  const float* __restrict__ s_src2,
                                                  const float* __restrict__ s_dst2,
                                                  float* __restrict__ Zpart,
                                                  float* __restrict__ part) {
  __shared__ float sd[4][1536];   // 24 KB
  int t = threadIdx.x;
  int h = t >> 6, lane = t & 63, m = lane & 15, quad = lane >> 4;
  int bx = blockIdx.x;
  int slice = bx & 3, mt = bx >> 2;
  int i0 = mt << 4, kbase = slice * 1536;
  {
    const float4* g = (const float4*)s_dst2;
    float4* l = (float4*)sd;
    int kb4 = kbase >> 2;
    #pragma unroll
    for (int k6 = 0; k6 < 6; ++k6) {
      int u = t + (k6 << 8);
      int hx = u / 384, uu = u - hx * 384;
      l[hx * 384 + uu] = g[hx * 1536 + kb4 + uu];
    }
  }
  float ssrc2 = s_src2[h * N_NODES + i0 + m];
  __syncthreads();

  const uint32* mrow = maskw + (size_t)(i0 + m) * 192 + slice * 48;
  const unsigned short* hp0 = hfT + (size_t)(h * 32 + m) * N_NODES + kbase + (quad << 3);
  const unsigned short* hp1 = hp0 + (size_t)16 * N_NODES;
  f32x4 acc0 = {0.f, 0.f, 0.f, 0.f}, acc1 = {0.f, 0.f, 0.f, 0.f};
  f32x4 accz = {0.f, 0.f, 0.f, 0.f};
  union { uint32 u[4]; short8 v; } ones;
  #pragma unroll
  for (int q = 0; q < 4; ++q) ones.u[q] = 0x3F803F80u;
  int sh = quad << 3;

  uint4 mcur = *(const uint4*)mrow;
  int4 hc[8];
  #pragma unroll
  for (int u = 0; u < 4; ++u) {
    hc[2 * u]     = *(const int4*)(hp0 + (u << 5));
    hc[2 * u + 1] = *(const int4*)(hp1 + (u << 5));
  }

  #pragma unroll 2
  for (int ob = 0; ob < 12; ++ob) {
    int nob = ob < 11 ? ob + 1 : 11;           // clamped: loads always issued
    uint4 mnxt = *(const uint4*)(mrow + (nob << 2));
    int4 hn[8];
    #pragma unroll
    for (int u = 0; u < 4; ++u) {
      int kk = (nob << 7) + (u << 5);
      hn[2 * u]     = *(const int4*)(hp0 + kk);
      hn[2 * u + 1] = *(const int4*)(hp1 + kk);
    }
    uint32 mws[4] = {mcur.x, mcur.y, mcur.z, mcur.w};
    #pragma unroll
    for (int u = 0; u < 4; ++u) {
      int it = (ob << 2) + u;
      uint32 bits = (mws[u] >> sh) & 0xffu;
      int base = (it << 5) + sh;
      f32x4 d0 = *(f32x4*)&sd[h][base];
      f32x4 d1 = *(f32x4*)&sd[h][base + 4];
      float dv[8] = {d0[0], d0[1], d0[2], d0[3], d1[0], d1[1], d1[2], d1[3]};
      float w[8];
      #pragma unroll
      for (int j = 0; j < 8; ++j) {
        float e = ssrc2 + dv[j];                 // (s_src+s_dst)*log2e
        float lr = fmaxf(e, 0.2f * e);           // leaky-relu (log2 domain)
        float ex = __ocml_native_exp2_f32(lr);   // v_exp_f32
        w[j] = (bits & (1u << j)) ? ex : 0.f;
      }
      union { uint32 u4[4]; short8 v; } afr;
      #pragma unroll
      for (int j = 0; j < 4; ++j) afr.u4[j] = pack2bf(w[2 * j], w[2 * j + 1]);
      union { int4 i; short8 v; } b0, b1;
      b0.i = hc[2 * u]; b1.i = hc[2 * u + 1];
      acc0 = __builtin_amdgcn_mfma_f32_16x16x32_bf16(afr.v, b0.v, acc0, 0, 0, 0);
      acc1 = __builtin_amdgcn_mfma_f32_16x16x32_bf16(afr.v, b1.v, acc1, 0, 0, 0);
      accz = __builtin_amdgcn_mfma_f32_16x16x32_bf16(afr.v, ones.v, accz, 0, 0, 0);
    }
    mcur = mnxt;
    #pragma unroll
    for (int q = 0; q < 8; ++q) hc[q] = hn[q];
  }
  if (m == 0) {
    #pragma unroll
    for (int r = 0; r < 4; ++r)
      Zpart[(size_t)(slice * 4 + h) * N_NODES + i0 + (quad << 2) + r] = accz[r];
  }
  float* pb = part + (size_t)slice * (N_NODES * 128) + h * (N_NODES * 32) +
              (size_t)i0 * 32;
  #pragma unroll
  for (int r = 0; r < 4; ++r) {
    int row = (quad << 2) + r;  // D layout: col=lane&15, row=quad*4+reg
    pb[row * 32 + m] = acc0[r];
    pb[row * 32 + 16 + m] = acc1[r];
  }
}

// K3: out = sum_s part[s] / sum_s Z[s]
__global__ __launch_bounds__(256) void k3_final(const float* __restrict__ part,
                                                const float* __restrict__ Zpart,
                                                float* __restrict__ out) {
  unsigned int idx4 = blockIdx.x * 256 + threadIdx.x;
  unsigned int h = idx4 / 49152u;
  unsigned int i = (idx4 - h * 49152u) >> 3;
  float z = 0.f;
  #pragma unroll
  for (int s = 0; s < 4; ++s) z += Zpart[(s * 4 + h) * N_NODES + i];
  f32x4 p = {0.f, 0.f, 0.f, 0.f};
  const f32x4* P = (const f32x4*)part;
  #pragma unroll
  for (int s = 0; s < 4; ++s) p += P[(size_t)s * 196608u + idx4];
  float rz = 1.0f / z;
  ((f32x4*)out)[idx4] = p * rz;
}

extern "C" void kernel_launch(void* const* d_in, const int* in_sizes, int n_in,
                              void* d_out, int out_size, void* d_ws, size_t ws_size,
                              hipStream_t stream) {
  const float* x = (const float*)d_in[0];
  const int* adj = (const int*)d_in[1];
  const float* W = (const float*)d_in[2];
  const float* a = (const float*)d_in[3];
  float* out = (float*)d_out;

  float* wsf = (float*)d_ws;
  unsigned short* hfT = (unsigned short*)wsf;       // 128*6144 bf16 (1.5 MB)
  float* s_src2 = wsf + 393216;                     // 4*6144
  float* s_dst2 = s_src2 + 24576;                   // 4*6144
  float* Zpart  = s_dst2 + 24576;                   // 16*6144
  float* part   = Zpart + 98304;                    // 4*786432 (12.6 MB)
  unsigned long long* maskbuf =
      (unsigned long long*)(part + 4 * 786432);     // 6144*96 u64 (4.7 MB)

  hipLaunchKernelGGL(k0_pack, dim3(1536), dim3(256), 0, stream, adj, maskbuf);
  hipLaunchKernelGGL(k1_feat, dim3(96), dim3(256), 0, stream, x, W, a, hfT, s_src2, s_dst2);
  hipLaunchKernelGGL(k2_attn, dim3(1536), dim3(256), 0, stream,
                     (const uint32*)maskbuf, hfT, s_src2, s_dst2, Zpart, part);
  hipLaunchKernelGGL(k3_final, dim3(768), dim3(256), 0, stream, part, Zpart, out);
}

// Round 5
// 334.448 us; speedup vs baseline: 1.0794x; 1.0432x over previous
//
#include <hip/hip_runtime.h>
#include <stdint.h>

#define N_NODES 6144
#define LOG2E 1.44269504088896f

typedef float f32x4 __attribute__((ext_vector_type(4)));
typedef short short8 __attribute__((ext_vector_type(8)));
typedef unsigned int uint32;

extern "C" __device__ float __ocml_native_exp2_f32(float);

// pack two floats -> two bf16 (round-half-up) in one u32: lo=a, hi=b
__device__ __forceinline__ unsigned int pack2bf(float a, float b) {
  unsigned int ua = __float_as_uint(a) + 0x8000u;
  unsigned int ub = __float_as_uint(b) + 0x8000u;
  return __builtin_amdgcn_perm(ub, ua, 0x07060302u);
}

// K0: bit-pack adjacency, one u32 word (32 edges) per thread.
// word id = row*192 + w ; bit j = adj[row*6144 + w*32 + j] > 0.
__global__ __launch_bounds__(256) void k0_pack(const int* __restrict__ adj,
                                               uint32* __restrict__ maskw) {
  unsigned int id = blockIdx.x * 256 + threadIdx.x;
  const int* src = adj + (size_t)id * 32;
  uint32 bits = 0;
  #pragma unroll
  for (int q = 0; q < 8; ++q) {
    int4 v = *(const int4*)(src + q * 4);
    bits |= (v.x > 0 ? 1u : 0u) << (4 * q);
    bits |= (v.y > 0 ? 1u : 0u) << (4 * q + 1);
    bits |= (v.z > 0 ? 1u : 0u) << (4 * q + 2);
    bits |= (v.w > 0 ? 1u : 0u) << (4 * q + 3);
  }
  maskw[id] = bits;
}

// K1: h = x*W (fp32). hfT (bf16 [c][n]) coalesced via LDS transpose;
// s_src2/s_dst2 = (h . a_{src,dst}) * log2(e).
__global__ __launch_bounds__(256) void k1_feat(const float* __restrict__ x,
                                               const float* __restrict__ W,
                                               const float* __restrict__ a,
                                               unsigned short* __restrict__ hfT,
                                               float* __restrict__ s_src2,
                                               float* __restrict__ s_dst2) {
  __shared__ float xl[64][132];
  __shared__ float Wl[64][128];
  int t = threadIdx.x;
  int n0 = blockIdx.x * 64;
  for (int u = t; u < 2048; u += 256) {
    int row = u >> 5, c4 = (u & 31) << 2;
    *(float4*)&xl[row][c4] = *(const float4*)(x + (size_t)(n0 + row) * 128 + c4);
  }
  int cg = t & 31, c0 = cg << 2;
  int ng = t >> 5, nb = ng << 3;
  float acc[8][4] = {};
  for (int ic = 0; ic < 2; ++ic) {
    __syncthreads();
    for (int u = t; u < 2048; u += 256) {
      int ii = u >> 5, c4 = (u & 31) << 2;
      int hh = c4 >> 5, d0 = c4 & 31;
      *(float4*)&Wl[ii][c4] = *(const float4*)(W + hh * 4096 + (ic * 64 + ii) * 32 + d0);
    }
    __syncthreads();
    #pragma unroll 4
    for (int ii = 0; ii < 64; ++ii) {
      float4 wv = *(float4*)&Wl[ii][c0];
      int i = ic * 64 + ii;
      #pragma unroll
      for (int r = 0; r < 8; ++r) {
        float xv = xl[nb + r][i];
        acc[r][0] += xv * wv.x; acc[r][1] += xv * wv.y;
        acc[r][2] += xv * wv.z; acc[r][3] += xv * wv.w;
      }
    }
  }
  __syncthreads();
  unsigned short* tb = (unsigned short*)&xl[0][0];   // bf16 [128][66]
  float* pb = &Wl[0][0];                             // float [2][64][33]
  int hh = c0 >> 5, d0 = c0 & 31;
  float4 adv = *(const float4*)(a + hh * 64 + d0);
  float4 asv = *(const float4*)(a + hh * 64 + 32 + d0);
  #pragma unroll
  for (int cc = 0; cc < 4; ++cc) {
    unsigned int* dst = (unsigned int*)(tb + (c0 + cc) * 66 + nb);
    #pragma unroll
    for (int p = 0; p < 4; ++p)
      dst[p] = pack2bf(acc[2 * p][cc], acc[2 * p + 1][cc]);
  }
  #pragma unroll
  for (int r = 0; r < 8; ++r) {
    float pd = acc[r][0] * adv.x + acc[r][1] * adv.y + acc[r][2] * adv.z + acc[r][3] * adv.w;
    float ps = acc[r][0] * asv.x + acc[r][1] * asv.y + acc[r][2] * asv.z + acc[r][3] * asv.w;
    pb[(nb + r) * 33 + cg] = pd;
    pb[2112 + (nb + r) * 33 + cg] = ps;
  }
  __syncthreads();
  {
    int row = t >> 1, half = t & 1;
    const unsigned int* s32 = (const unsigned int*)(tb + row * 66 + half * 32);
    unsigned int v[16];
    #pragma unroll
    for (int q = 0; q < 16; ++q) v[q] = s32[q];
    unsigned short* gdst = hfT + (size_t)row * N_NODES + n0 + half * 32;
    #pragma unroll
    for (int q = 0; q < 4; ++q) {
      uint4 w4; w4.x = v[4 * q]; w4.y = v[4 * q + 1]; w4.z = v[4 * q + 2]; w4.w = v[4 * q + 3];
      *(uint4*)(gdst + q * 8) = w4;
    }
  }
  for (int task = t; task < 512; task += 256) {
    int n = task & 63, hz = task >> 6;
    int h = hz & 3, sdx = hz >> 2;
    const float* src = pb + sdx * 2112 + n * 33 + h * 8;
    float s = src[0] + src[1] + src[2] + src[3] + src[4] + src[5] + src[6] + src[7];
    float* out = sdx ? s_src2 : s_dst2;
    out[h * N_NODES + n0 + n] = s * LOG2E;
  }
}

// one k-step: build 16x32 A-fragment weights in-register, 3 MFMAs
__device__ __forceinline__ void gat_step(uint32 bits8, f32x4 d0, f32x4 d1,
                                         float ssrc2, int4 B0, int4 B1,
                                         f32x4& acc0, f32x4& acc1, f32x4& accz,
                                         short8 onesv) {
  float w[8];
  float dv[8] = {d0[0], d0[1], d0[2], d0[3], d1[0], d1[1], d1[2], d1[3]};
  #pragma unroll
  for (int j = 0; j < 8; ++j) {
    float e = ssrc2 + dv[j];                 // (s_src+s_dst) * log2e
    float lr = fmaxf(e, 0.2f * e);           // leaky-relu (log2 domain)
    float ex = __ocml_native_exp2_f32(lr);   // v_exp_f32
    w[j] = (bits8 & (1u << j)) ? ex : 0.f;
  }
  union { uint32 u4[4]; short8 v; } afr;
  #pragma unroll
  for (int j = 0; j < 4; ++j) afr.u4[j] = pack2bf(w[2 * j], w[2 * j + 1]);
  union { int4 i; short8 v; } b0u, b1u;
  b0u.i = B0; b1u.i = B1;
  acc0 = __builtin_amdgcn_mfma_f32_16x16x32_bf16(afr.v, b0u.v, acc0, 0, 0, 0);
  acc1 = __builtin_amdgcn_mfma_f32_16x16x32_bf16(afr.v, b1u.v, acc1, 0, 0, 0);
  accz = __builtin_amdgcn_mfma_f32_16x16x32_bf16(afr.v, onesv, accz, 0, 0, 0);
}

// K2: fused masked-softmax aggregate. Block = 4 waves = 4 heads, 16-row m-tile,
// k-slice 1536 (split 4). Bitmask adj (L2), s_dst2 in LDS, depth-2 software
// pipeline with ALL state in named scalars (no arrays -> no scratch demotion).
__global__ __launch_bounds__(256) void k2_attn(const uint32* __restrict__ maskw,
                                               const unsigned short* __restrict__ hfT,
                                               const float* __restrict__ s_src2,
                                               const float* __restrict__ s_dst2,
                                               float* __restrict__ Zpart,
                                               float* __restrict__ part) {
  __shared__ float sd[4][1536];   // 24 KB
  int t = threadIdx.x;
  int h = t >> 6, lane = t & 63, m = lane & 15, quad = lane >> 4;
  int bx = blockIdx.x;
  int slice = bx & 3, mt = bx >> 2;
  int i0 = mt << 4, kbase = slice * 1536;
  {
    const float4* g = (const float4*)s_dst2;
    float4* l = (float4*)sd;
    int kb4 = kbase >> 2;
    #pragma unroll
    for (int k6 = 0; k6 < 6; ++k6) {
      int u = t + (k6 << 8);
      int hx = u / 384, uu = u - hx * 384;
      l[hx * 384 + uu] = g[hx * 1536 + kb4 + uu];
    }
  }
  float ssrc2 = s_src2[h * N_NODES + i0 + m];
  __syncthreads();

  const uint32* mrow = maskw + (size_t)(i0 + m) * 192 + slice * 48;  // 1 word/iter
  const unsigned short* hp0 = hfT + (size_t)(h * 32 + m) * N_NODES + kbase + (quad << 3);
  const unsigned short* hp1 = hp0 + (size_t)16 * N_NODES;
  int sh = quad << 3;
  f32x4 acc0 = {0.f, 0.f, 0.f, 0.f}, acc1 = {0.f, 0.f, 0.f, 0.f};
  f32x4 accz = {0.f, 0.f, 0.f, 0.f};
  union { uint32 u[4]; short8 v; } ones;
  #pragma unroll
  for (int q = 0; q < 4; ++q) ones.u[q] = 0x3F803F80u;

  // pipeline prologue: stages for it=0 and it=1
  int4 cA0 = *(const int4*)(hp0);
  int4 cB0 = *(const int4*)(hp1);
  uint32 cw0 = mrow[0];
  int4 cA1 = *(const int4*)(hp0 + 32);
  int4 cB1 = *(const int4*)(hp1 + 32);
  uint32 cw1 = mrow[1];
  f32x4 dd0 = *(f32x4*)&sd[h][sh];
  f32x4 dd1 = *(f32x4*)&sd[h][sh + 4];

  for (int it = 0; it < 48; it += 2) {
    // prefetch stage it+2
    int p2 = (it + 2 < 48) ? it + 2 : 46;
    int4 nA0 = *(const int4*)(hp0 + (p2 << 5));
    int4 nB0 = *(const int4*)(hp1 + (p2 << 5));
    uint32 nw0 = mrow[p2];
    // sd for it+1
    int b1i = ((it + 1) << 5) + sh;
    f32x4 e0 = *(f32x4*)&sd[h][b1i];
    f32x4 e1 = *(f32x4*)&sd[h][b1i + 4];
    gat_step((cw0 >> sh) & 0xffu, dd0, dd1, ssrc2, cA0, cB0, acc0, acc1, accz, ones.v);
    cA0 = nA0; cB0 = nB0; cw0 = nw0;
    // prefetch stage it+3
    int p3 = (it + 3 < 48) ? it + 3 : 47;
    int4 nA1 = *(const int4*)(hp0 + (p3 << 5));
    int4 nB1 = *(const int4*)(hp1 + (p3 << 5));
    uint32 nw1 = mrow[p3];
    // sd for it+2
    int p2c = (it + 2 < 48) ? it + 2 : 46;
    int b2i = (p2c << 5) + sh;
    f32x4 f0 = *(f32x4*)&sd[h][b2i];
    f32x4 f1 = *(f32x4*)&sd[h][b2i + 4];
    gat_step((cw1 >> sh) & 0xffu, e0, e1, ssrc2, cA1, cB1, acc0, acc1, accz, ones.v);
    cA1 = nA1; cB1 = nB1; cw1 = nw1;
    dd0 = f0; dd1 = f1;
  }

  if (m == 0) {
    #pragma unroll
    for (int r = 0; r < 4; ++r)
      Zpart[(size_t)(slice * 4 + h) * N_NODES + i0 + (quad << 2) + r] = accz[r];
  }
  float* pb = part + (size_t)slice * (N_NODES * 128) + h * (N_NODES * 32) +
              (size_t)i0 * 32;
  #pragma unroll
  for (int r = 0; r < 4; ++r) {
    int row = (quad << 2) + r;  // D layout: col=lane&15, row=quad*4+reg
    pb[row * 32 + m] = acc0[r];
    pb[row * 32 + 16 + m] = acc1[r];
  }
}

// K3: out = sum_s part[s] / sum_s Z[s]
__global__ __launch_bounds__(256) void k3_final(const float* __restrict__ part,
                                                const float* __restrict__ Zpart,
                                                float* __restrict__ out) {
  unsigned int idx4 = blockIdx.x * 256 + threadIdx.x;
  unsigned int h = idx4 / 49152u;
  unsigned int i = (idx4 - h * 49152u) >> 3;
  float z = 0.f;
  #pragma unroll
  for (int s = 0; s < 4; ++s) z += Zpart[(s * 4 + h) * N_NODES + i];
  f32x4 p = {0.f, 0.f, 0.f, 0.f};
  const f32x4* P = (const f32x4*)part;
  #pragma unroll
  for (int s = 0; s < 4; ++s) p += P[(size_t)s * 196608u + idx4];
  float rz = 1.0f / z;
  ((f32x4*)out)[idx4] = p * rz;
}

extern "C" void kernel_launch(void* const* d_in, const int* in_sizes, int n_in,
                              void* d_out, int out_size, void* d_ws, size_t ws_size,
                              hipStream_t stream) {
  const float* x = (const float*)d_in[0];
  const int* adj = (const int*)d_in[1];
  const float* W = (const float*)d_in[2];
  const float* a = (const float*)d_in[3];
  float* out = (float*)d_out;

  float* wsf = (float*)d_ws;
  unsigned short* hfT = (unsigned short*)wsf;       // 128*6144 bf16 (1.5 MB)
  float* s_src2 = wsf + 393216;                     // 4*6144
  float* s_dst2 = s_src2 + 24576;                   // 4*6144
  float* Zpart  = s_dst2 + 24576;                   // 16*6144
  float* part   = Zpart + 98304;                    // 4*786432 (12.6 MB)
  uint32* maskw = (uint32*)(part + 4 * 786432);     // 6144*192 u32 (4.7 MB)

  hipLaunchKernelGGL(k0_pack, dim3(4608), dim3(256), 0, stream, adj, maskw);
  hipLaunchKernelGGL(k1_feat, dim3(96), dim3(256), 0, stream, x, W, a, hfT, s_src2, s_dst2);
  hipLaunchKernelGGL(k2_attn, dim3(1536), dim3(256), 0, stream,
                     maskw, hfT, s_src2, s_dst2, Zpart, part);
  hipLaunchKernelGGL(k3_final, dim3(768), dim3(256), 0, stream, part, Zpart, out);
}

// Round 6
// 311.383 us; speedup vs baseline: 1.1593x; 1.0741x over previous
//
#include <hip/hip_runtime.h>
#include <stdint.h>

#define N_NODES 6144
#define LOG2E 1.44269504088896f

typedef float f32x4 __attribute__((ext_vector_type(4)));
typedef short short8 __attribute__((ext_vector_type(8)));
typedef unsigned int uint32;

extern "C" __device__ float __ocml_native_exp2_f32(float);

// pack two floats -> two bf16 (round-half-up) in one u32: lo=a, hi=b
__device__ __forceinline__ unsigned int pack2bf(float a, float b) {
  unsigned int ua = __float_as_uint(a) + 0x8000u;
  unsigned int ub = __float_as_uint(b) + 0x8000u;
  return __builtin_amdgcn_perm(ub, ua, 0x07060302u);
}

// K1: h = x*W (fp32). hfT (bf16 [c][n]) coalesced via LDS transpose;
// s_src2/s_dst2 = (h . a_{src,dst}) * log2(e).
__global__ __launch_bounds__(256) void k1_feat(const float* __restrict__ x,
                                               const float* __restrict__ W,
                                               const float* __restrict__ a,
                                               unsigned short* __restrict__ hfT,
                                               float* __restrict__ s_src2,
                                               float* __restrict__ s_dst2) {
  __shared__ float xl[64][132];
  __shared__ float Wl[64][128];
  int t = threadIdx.x;
  int n0 = blockIdx.x * 64;
  for (int u = t; u < 2048; u += 256) {
    int row = u >> 5, c4 = (u & 31) << 2;
    *(float4*)&xl[row][c4] = *(const float4*)(x + (size_t)(n0 + row) * 128 + c4);
  }
  int cg = t & 31, c0 = cg << 2;
  int ng = t >> 5, nb = ng << 3;
  float acc[8][4] = {};
  for (int ic = 0; ic < 2; ++ic) {
    __syncthreads();
    for (int u = t; u < 2048; u += 256) {
      int ii = u >> 5, c4 = (u & 31) << 2;
      int hh = c4 >> 5, d0 = c4 & 31;
      *(float4*)&Wl[ii][c4] = *(const float4*)(W + hh * 4096 + (ic * 64 + ii) * 32 + d0);
    }
    __syncthreads();
    #pragma unroll 4
    for (int ii = 0; ii < 64; ++ii) {
      float4 wv = *(float4*)&Wl[ii][c0];
      int i = ic * 64 + ii;
      #pragma unroll
      for (int r = 0; r < 8; ++r) {
        float xv = xl[nb + r][i];
        acc[r][0] += xv * wv.x; acc[r][1] += xv * wv.y;
        acc[r][2] += xv * wv.z; acc[r][3] += xv * wv.w;
      }
    }
  }
  __syncthreads();
  unsigned short* tb = (unsigned short*)&xl[0][0];   // bf16 [128][66]
  float* pb = &Wl[0][0];                             // float [2][64][33]
  int hh = c0 >> 5, d0 = c0 & 31;
  float4 adv = *(const float4*)(a + hh * 64 + d0);
  float4 asv = *(const float4*)(a + hh * 64 + 32 + d0);
  #pragma unroll
  for (int cc = 0; cc < 4; ++cc) {
    unsigned int* dst = (unsigned int*)(tb + (c0 + cc) * 66 + nb);
    #pragma unroll
    for (int p = 0; p < 4; ++p)
      dst[p] = pack2bf(acc[2 * p][cc], acc[2 * p + 1][cc]);
  }
  #pragma unroll
  for (int r = 0; r < 8; ++r) {
    float pd = acc[r][0] * adv.x + acc[r][1] * adv.y + acc[r][2] * adv.z + acc[r][3] * adv.w;
    float ps = acc[r][0] * asv.x + acc[r][1] * asv.y + acc[r][2] * asv.z + acc[r][3] * asv.w;
    pb[(nb + r) * 33 + cg] = pd;
    pb[2112 + (nb + r) * 33 + cg] = ps;
  }
  __syncthreads();
  {
    int row = t >> 1, half = t & 1;
    const unsigned int* s32 = (const unsigned int*)(tb + row * 66 + half * 32);
    unsigned int v[16];
    #pragma unroll
    for (int q = 0; q < 16; ++q) v[q] = s32[q];
    unsigned short* gdst = hfT + (size_t)row * N_NODES + n0 + half * 32;
    #pragma unroll
    for (int q = 0; q < 4; ++q) {
      uint4 w4; w4.x = v[4 * q]; w4.y = v[4 * q + 1]; w4.z = v[4 * q + 2]; w4.w = v[4 * q + 3];
      *(uint4*)(gdst + q * 8) = w4;
    }
  }
  for (int task = t; task < 512; task += 256) {
    int n = task & 63, hz = task >> 6;
    int h = hz & 3, sdx = hz >> 2;
    const float* src = pb + sdx * 2112 + n * 33 + h * 8;
    float s = src[0] + src[1] + src[2] + src[3] + src[4] + src[5] + src[6] + src[7];
    float* out = sdx ? s_src2 : s_dst2;
    out[h * N_NODES + n0 + n] = s * LOG2E;
  }
}

// one m-tile k-step: build 16x32 A-fragment weights in-register, 2 MFMAs + Z tree
__device__ __forceinline__ void gat_tile(float ss, int4 At0, int4 At1,
                                         const float (&dv)[8], short8 b0, short8 b1,
                                         f32x4& a0, f32x4& a1, float& zacc) {
  int av[8] = {At0.x, At0.y, At0.z, At0.w, At1.x, At1.y, At1.z, At1.w};
  float w[8];
  #pragma unroll
  for (int j = 0; j < 8; ++j) {
    float e = ss + dv[j];                    // (s_src+s_dst) * log2e
    float lr = fmaxf(e, 0.2f * e);           // leaky-relu (log2 domain)
    float ex = __ocml_native_exp2_f32(lr);   // v_exp_f32
    w[j] = (av[j] > 0) ? ex : 0.f;
  }
  zacc += ((w[0] + w[1]) + (w[2] + w[3])) + ((w[4] + w[5]) + (w[6] + w[7]));
  union { uint32 u4[4]; short8 v; } afr;
  #pragma unroll
  for (int j = 0; j < 4; ++j) afr.u4[j] = pack2bf(w[2 * j], w[2 * j + 1]);
  a0 = __builtin_amdgcn_mfma_f32_16x16x32_bf16(afr.v, b0, a0, 0, 0, 0);
  a1 = __builtin_amdgcn_mfma_f32_16x16x32_bf16(afr.v, b1, a1, 0, 0, 0);
}

// K2: fused masked-softmax aggregate, adjacency read in-line (exactly once).
// Block = 4 waves = 4 heads x 64 rows (4 m-tiles) x k-slice 768 (split 8).
// B-fragments + s_dst shared across the 4 m-tiles => ~700 cyc VALU per load
// batch; depth-1 named-scalar prefetch + sched_barrier(0) stops load-sinking.
// Partials/Z accumulated via atomicAdd across the 8 k-slices.
__global__ __launch_bounds__(256) void k2_attn(const int* __restrict__ adj,
                                               const unsigned short* __restrict__ hfT,
                                               const float* __restrict__ s_src2,
                                               const float* __restrict__ s_dst2,
                                               float* __restrict__ Zpart,
                                               float* __restrict__ part) {
  __shared__ float sd[4][768];   // 12 KB
  int t = threadIdx.x;
  int h = t >> 6, lane = t & 63, m = lane & 15, quad = lane >> 4;
  int bx = blockIdx.x;
  int slice = bx & 7, mg = bx >> 3;
  int i0 = mg << 6;                 // 64 rows
  int kbase = slice * 768;          // 24 k-steps of 32
  {
    const float4* g = (const float4*)s_dst2;
    float4* l = (float4*)sd;
    int kb4 = kbase >> 2;
    #pragma unroll
    for (int r = 0; r < 3; ++r) {
      int u = t + (r << 8);
      int hx = u / 192, uu = u - hx * 192;
      l[hx * 192 + uu] = g[hx * 1536 + kb4 + uu];
    }
  }
  float ss0 = s_src2[h * N_NODES + i0 + m];
  float ss1 = s_src2[h * N_NODES + i0 + 16 + m];
  float ss2 = s_src2[h * N_NODES + i0 + 32 + m];
  float ss3 = s_src2[h * N_NODES + i0 + 48 + m];
  __syncthreads();

  int sh = quad << 3;
  const unsigned short* hp0 = hfT + (size_t)(h * 32 + m) * N_NODES + kbase + sh;
  const unsigned short* hp1 = hp0 + (size_t)16 * N_NODES;
  const int* ar0 = adj + (size_t)(i0 + m) * N_NODES + kbase + sh;
  const int* ar1 = ar0 + 16 * N_NODES;
  const int* ar2 = ar0 + 32 * N_NODES;
  const int* ar3 = ar0 + 48 * N_NODES;

  f32x4 acc00 = {0,0,0,0}, acc01 = {0,0,0,0};
  f32x4 acc10 = {0,0,0,0}, acc11 = {0,0,0,0};
  f32x4 acc20 = {0,0,0,0}, acc21 = {0,0,0,0};
  f32x4 acc30 = {0,0,0,0}, acc31 = {0,0,0,0};
  float z0 = 0.f, z1 = 0.f, z2 = 0.f, z3 = 0.f;

  // prologue: loads for it=0
  int4 cB0 = *(const int4*)hp0;
  int4 cB1 = *(const int4*)hp1;
  int4 cA00 = *(const int4*)ar0, cA01 = *(const int4*)(ar0 + 4);
  int4 cA10 = *(const int4*)ar1, cA11 = *(const int4*)(ar1 + 4);
  int4 cA20 = *(const int4*)ar2, cA21 = *(const int4*)(ar2 + 4);
  int4 cA30 = *(const int4*)ar3, cA31 = *(const int4*)(ar3 + 4);
  f32x4 cd0 = *(f32x4*)&sd[h][sh];
  f32x4 cd1 = *(f32x4*)&sd[h][sh + 4];

  #pragma unroll 1
  for (int it = 0; it < 24; ++it) {
    int kn = ((it + 1 < 24) ? it + 1 : 23) << 5;
    int4 nB0 = *(const int4*)(hp0 + kn);
    int4 nB1 = *(const int4*)(hp1 + kn);
    int4 nA00 = *(const int4*)(ar0 + kn), nA01 = *(const int4*)(ar0 + kn + 4);
    int4 nA10 = *(const int4*)(ar1 + kn), nA11 = *(const int4*)(ar1 + kn + 4);
    int4 nA20 = *(const int4*)(ar2 + kn), nA21 = *(const int4*)(ar2 + kn + 4);
    int4 nA30 = *(const int4*)(ar3 + kn), nA31 = *(const int4*)(ar3 + kn + 4);
    f32x4 nd0 = *(f32x4*)&sd[h][kn + sh];
    f32x4 nd1 = *(f32x4*)&sd[h][kn + sh + 4];
    __builtin_amdgcn_sched_barrier(0);   // keep prefetch issued before compute

    float dv[8] = {cd0[0], cd0[1], cd0[2], cd0[3], cd1[0], cd1[1], cd1[2], cd1[3]};
    union { int4 i; short8 v; } b0, b1;
    b0.i = cB0; b1.i = cB1;
    gat_tile(ss0, cA00, cA01, dv, b0.v, b1.v, acc00, acc01, z0);
    gat_tile(ss1, cA10, cA11, dv, b0.v, b1.v, acc10, acc11, z1);
    gat_tile(ss2, cA20, cA21, dv, b0.v, b1.v, acc20, acc21, z2);
    gat_tile(ss3, cA30, cA31, dv, b0.v, b1.v, acc30, acc31, z3);

    cB0 = nB0; cB1 = nB1;
    cA00 = nA00; cA01 = nA01; cA10 = nA10; cA11 = nA11;
    cA20 = nA20; cA21 = nA21; cA30 = nA30; cA31 = nA31;
    cd0 = nd0; cd1 = nd1;
  }

  // Z: reduce quads (k-partials) -> lanes 0-15 hold row sums per tile
  z0 += __shfl_xor(z0, 16); z0 += __shfl_xor(z0, 32);
  z1 += __shfl_xor(z1, 16); z1 += __shfl_xor(z1, 32);
  z2 += __shfl_xor(z2, 16); z2 += __shfl_xor(z2, 32);
  z3 += __shfl_xor(z3, 16); z3 += __shfl_xor(z3, 32);
  if (lane < 16) {
    float* zb = Zpart + h * N_NODES + i0 + m;
    atomicAdd(zb, z0);
    atomicAdd(zb + 16, z1);
    atomicAdd(zb + 32, z2);
    atomicAdd(zb + 48, z3);
  }
  // partials: (h, row, col) flat layout; D: col=lane&15, row=quad*4+reg
  float* pb = part + (size_t)h * (N_NODES * 32) + (size_t)i0 * 32;
  #pragma unroll
  for (int r = 0; r < 4; ++r) {
    int row = (quad << 2) + r;
    atomicAdd(&pb[row * 32 + m], acc00[r]);
    atomicAdd(&pb[row * 32 + 16 + m], acc01[r]);
    atomicAdd(&pb[(16 + row) * 32 + m], acc10[r]);
    atomicAdd(&pb[(16 + row) * 32 + 16 + m], acc11[r]);
    atomicAdd(&pb[(32 + row) * 32 + m], acc20[r]);
    atomicAdd(&pb[(32 + row) * 32 + 16 + m], acc21[r]);
    atomicAdd(&pb[(48 + row) * 32 + m], acc30[r]);
    atomicAdd(&pb[(48 + row) * 32 + 16 + m], acc31[r]);
  }
}

// K3: out = part / Z
__global__ __launch_bounds__(256) void k3_final(const float* __restrict__ part,
                                                const float* __restrict__ Zpart,
                                                float* __restrict__ out) {
  unsigned int idx4 = blockIdx.x * 256 + threadIdx.x;   // float4 index
  unsigned int h = idx4 / 49152u;
  unsigned int i = (idx4 - h * 49152u) >> 3;
  float rz = 1.0f / Zpart[h * N_NODES + i];
  f32x4 p = ((const f32x4*)part)[idx4];
  ((f32x4*)out)[idx4] = p * rz;
}

extern "C" void kernel_launch(void* const* d_in, const int* in_sizes, int n_in,
                              void* d_out, int out_size, void* d_ws, size_t ws_size,
                              hipStream_t stream) {
  const float* x = (const float*)d_in[0];
  const int* adj = (const int*)d_in[1];
  const float* W = (const float*)d_in[2];
  const float* a = (const float*)d_in[3];
  float* out = (float*)d_out;

  float* wsf = (float*)d_ws;
  unsigned short* hfT = (unsigned short*)wsf;       // 128*6144 bf16 (1.5 MB)
  float* s_src2 = wsf + 393216;                     // 4*6144
  float* s_dst2 = s_src2 + 24576;                   // 4*6144
  float* part   = s_dst2 + 24576;                   // 786432 (3 MB)
  float* Zpart  = part + 786432;                    // 4*6144
  // total ~5 MB of d_ws

  hipMemsetAsync(part, 0, (786432 + 24576) * sizeof(float), stream);
  hipLaunchKernelGGL(k1_feat, dim3(96), dim3(256), 0, stream, x, W, a, hfT, s_src2, s_dst2);
  hipLaunchKernelGGL(k2_attn, dim3(768), dim3(256), 0, stream,
                     adj, hfT, s_src2, s_dst2, Zpart, part);
  hipLaunchKernelGGL(k3_final, dim3(768), dim3(256), 0, stream, part, Zpart, out);
}

// Round 8
// 309.008 us; speedup vs baseline: 1.1682x; 1.0077x over previous
//
#include <hip/hip_runtime.h>
#include <stdint.h>

#define N_NODES 6144
#define LOG2E 1.44269504088896f

typedef float f32x4 __attribute__((ext_vector_type(4)));
typedef short short8 __attribute__((ext_vector_type(8)));
typedef unsigned int uint32;

extern "C" __device__ float __ocml_native_exp2_f32(float);

// pack two floats -> two bf16 (round-half-up) in one u32: lo=a, hi=b
__device__ __forceinline__ unsigned int pack2bf(float a, float b) {
  unsigned int ua = __float_as_uint(a) + 0x8000u;
  unsigned int ub = __float_as_uint(b) + 0x8000u;
  return __builtin_amdgcn_perm(ub, ua, 0x07060302u);
}

// K0: bit-pack adjacency, one u32 word (32 edges) per thread.
// word id = row*192 + w ; bit j = adj[row*6144 + w*32 + j] != 0.
__global__ __launch_bounds__(256) void k0_pack(const int* __restrict__ adj,
                                               uint32* __restrict__ maskw) {
  unsigned int id = blockIdx.x * 256 + threadIdx.x;
  const int* src = adj + (size_t)id * 32;
  uint32 bits = 0;
  #pragma unroll
  for (int q = 0; q < 8; ++q) {
    int4 v = *(const int4*)(src + q * 4);
    bits |= (v.x != 0 ? 1u : 0u) << (4 * q);
    bits |= (v.y != 0 ? 1u : 0u) << (4 * q + 1);
    bits |= (v.z != 0 ? 1u : 0u) << (4 * q + 2);
    bits |= (v.w != 0 ? 1u : 0u) << (4 * q + 3);
  }
  maskw[id] = bits;
}

// K1: h = x*W (fp32). hfT (bf16 [c][n]) coalesced via LDS transpose;
// s_src2/s_dst2 = (h . a_{src,dst}) * log2(e).
__global__ __launch_bounds__(256) void k1_feat(const float* __restrict__ x,
                                               const float* __restrict__ W,
                                               const float* __restrict__ a,
                                               unsigned short* __restrict__ hfT,
                                               float* __restrict__ s_src2,
                                               float* __restrict__ s_dst2) {
  __shared__ float xl[64][132];
  __shared__ float Wl[64][128];
  int t = threadIdx.x;
  int n0 = blockIdx.x * 64;
  for (int u = t; u < 2048; u += 256) {
    int row = u >> 5, c4 = (u & 31) << 2;
    *(float4*)&xl[row][c4] = *(const float4*)(x + (size_t)(n0 + row) * 128 + c4);
  }
  int cg = t & 31, c0 = cg << 2;
  int ng = t >> 5, nb = ng << 3;
  float acc[8][4] = {};
  for (int ic = 0; ic < 2; ++ic) {
    __syncthreads();
    for (int u = t; u < 2048; u += 256) {
      int ii = u >> 5, c4 = (u & 31) << 2;
      int hh = c4 >> 5, d0 = c4 & 31;
      *(float4*)&Wl[ii][c4] = *(const float4*)(W + hh * 4096 + (ic * 64 + ii) * 32 + d0);
    }
    __syncthreads();
    #pragma unroll 4
    for (int ii = 0; ii < 64; ++ii) {
      float4 wv = *(float4*)&Wl[ii][c0];
      int i = ic * 64 + ii;
      #pragma unroll
      for (int r = 0; r < 8; ++r) {
        float xv = xl[nb + r][i];
        acc[r][0] += xv * wv.x; acc[r][1] += xv * wv.y;
        acc[r][2] += xv * wv.z; acc[r][3] += xv * wv.w;
      }
    }
  }
  __syncthreads();
  unsigned short* tb = (unsigned short*)&xl[0][0];   // bf16 [128][66]
  float* pb = &Wl[0][0];                             // float [2][64][33]
  int hh = c0 >> 5, d0 = c0 & 31;
  float4 adv = *(const float4*)(a + hh * 64 + d0);
  float4 asv = *(const float4*)(a + hh * 64 + 32 + d0);
  #pragma unroll
  for (int cc = 0; cc < 4; ++cc) {
    unsigned int* dst = (unsigned int*)(tb + (c0 + cc) * 66 + nb);
    #pragma unroll
    for (int p = 0; p < 4; ++p)
      dst[p] = pack2bf(acc[2 * p][cc], acc[2 * p + 1][cc]);
  }
  #pragma unroll
  for (int r = 0; r < 8; ++r) {
    float pd = acc[r][0] * adv.x + acc[r][1] * adv.y + acc[r][2] * adv.z + acc[r][3] * adv.w;
    float ps = acc[r][0] * asv.x + acc[r][1] * asv.y + acc[r][2] * asv.z + acc[r][3] * asv.w;
    pb[(nb + r) * 33 + cg] = pd;
    pb[2112 + (nb + r) * 33 + cg] = ps;
  }
  __syncthreads();
  {
    int row = t >> 1, half = t & 1;
    const unsigned int* s32 = (const unsigned int*)(tb + row * 66 + half * 32);
    unsigned int v[16];
    #pragma unroll
    for (int q = 0; q < 16; ++q) v[q] = s32[q];
    unsigned short* gdst = hfT + (size_t)row * N_NODES + n0 + half * 32;
    #pragma unroll
    for (int q = 0; q < 4; ++q) {
      uint4 w4; w4.x = v[4 * q]; w4.y = v[4 * q + 1]; w4.z = v[4 * q + 2]; w4.w = v[4 * q + 3];
      *(uint4*)(gdst + q * 8) = w4;
    }
  }
  for (int task = t; task < 512; task += 256) {
    int n = task & 63, hz = task >> 6;
    int h = hz & 3, sdx = hz >> 2;
    const float* src = pb + sdx * 2112 + n * 33 + h * 8;
    float s = src[0] + src[1] + src[2] + src[3] + src[4] + src[5] + src[6] + src[7];
    float* out = sdx ? s_src2 : s_dst2;
    out[h * N_NODES + n0 + n] = s * LOG2E;
  }
}

// one m-tile k-step: 16x32 A-fragment weights in-register, 2 MFMAs + z tree
__device__ __forceinline__ void gat_tile(float ss, uint32 bits8,
                                         const float (&dv)[8], short8 b0, short8 b1,
                                         f32x4& a0, f32x4& a1, float& zacc) {
  float w[8];
  #pragma unroll
  for (int j = 0; j < 8; ++j) {
    float e = ss + dv[j];                    // (s_src+s_dst) * log2e
    float lr = fmaxf(e, 0.2f * e);           // leaky-relu (log2 domain)
    float ex = __ocml_native_exp2_f32(lr);   // v_exp_f32
    w[j] = (bits8 & (1u << j)) ? ex : 0.f;
  }
  zacc += ((w[0] + w[1]) + (w[2] + w[3])) + ((w[4] + w[5]) + (w[6] + w[7]));
  union { uint32 u4[4]; short8 v; } afr;
  #pragma unroll
  for (int j = 0; j < 4; ++j) afr.u4[j] = pack2bf(w[2 * j], w[2 * j + 1]);
  a0 = __builtin_amdgcn_mfma_f32_16x16x32_bf16(afr.v, b0, a0, 0, 0, 0);
  a1 = __builtin_amdgcn_mfma_f32_16x16x32_bf16(afr.v, b1, a1, 0, 0, 0);
}

__device__ __forceinline__ void gat_step4(
    uint32 w0, uint32 w1, uint32 w2, uint32 w3, int sh,
    f32x4 d0, f32x4 d1, int4 B0i, int4 B1i,
    float ss0, float ss1, float ss2, float ss3,
    f32x4& a00, f32x4& a01, f32x4& a10, f32x4& a11,
    f32x4& a20, f32x4& a21, f32x4& a30, f32x4& a31,
    float& z0, float& z1, float& z2, float& z3) {
  float dv[8] = {d0[0], d0[1], d0[2], d0[3], d1[0], d1[1], d1[2], d1[3]};
  union { int4 i; short8 v; } b0u, b1u;
  b0u.i = B0i; b1u.i = B1i;
  gat_tile(ss0, (w0 >> sh) & 0xffu, dv, b0u.v, b1u.v, a00, a01, z0);
  gat_tile(ss1, (w1 >> sh) & 0xffu, dv, b0u.v, b1u.v, a10, a11, z1);
  gat_tile(ss2, (w2 >> sh) & 0xffu, dv, b0u.v, b1u.v, a20, a21, z2);
  gat_tile(ss3, (w3 >> sh) & 0xffu, dv, b0u.v, b1u.v, a30, a31, z3);
}

// K2: fused masked-softmax aggregate. Block = 4 waves = 4 heads x 64 rows
// (4 m-tiles) x k-slice 384 (split 16). Bitmask adj (L2-resident), hfT L2,
// s_dst in LDS. Unroll-2 two-stage rotation: no loop-carried copies.
__global__ __launch_bounds__(256) void k2_attn(const uint32* __restrict__ maskw,
                                               const unsigned short* __restrict__ hfT,
                                               const float* __restrict__ s_src2,
                                               const float* __restrict__ s_dst2,
                                               float* __restrict__ Zpart,
                                               float* __restrict__ part) {
  __shared__ float sd[4][384];   // 6 KB
  int t = threadIdx.x;
  int h = t >> 6, lane = t & 63, m = lane & 15, quad = lane >> 4;
  int bx = blockIdx.x;
  int slice = bx & 15, mg = bx >> 4;    // slice-major
  int i0 = mg << 6;                     // 64 rows
  int kbase = slice * 384;              // 12 k-steps of 32
  {
    const float4* g = (const float4*)s_dst2;
    float4* l = (float4*)sd;
    int kb4 = kbase >> 2;
    for (int u = t; u < 384; u += 256) {
      int hx = u / 96, uu = u - hx * 96;
      l[hx * 96 + uu] = g[hx * 1536 + kb4 + uu];
    }
  }
  float ss0 = s_src2[h * N_NODES + i0 + m];
  float ss1 = s_src2[h * N_NODES + i0 + 16 + m];
  float ss2 = s_src2[h * N_NODES + i0 + 32 + m];
  float ss3 = s_src2[h * N_NODES + i0 + 48 + m];
  __syncthreads();

  int sh = quad << 3;
  const unsigned short* hp0 = hfT + (size_t)(h * 32 + m) * N_NODES + kbase + sh;
  const unsigned short* hp1 = hp0 + (size_t)16 * N_NODES;
  const uint32* mr0 = maskw + (size_t)(i0 + m) * 192 + slice * 12;
  const uint32* mr1 = mr0 + 16 * 192;
  const uint32* mr2 = mr0 + 32 * 192;
  const uint32* mr3 = mr0 + 48 * 192;
  const float* sdh = &sd[h][0];

  f32x4 a00 = {0,0,0,0}, a01 = {0,0,0,0};
  f32x4 a10 = {0,0,0,0}, a11 = {0,0,0,0};
  f32x4 a20 = {0,0,0,0}, a21 = {0,0,0,0};
  f32x4 a30 = {0,0,0,0}, a31 = {0,0,0,0};
  float z0 = 0.f, z1 = 0.f, z2 = 0.f, z3 = 0.f;

  // prologue: A-set loads for step 0
  int4 Ba0 = *(const int4*)hp0;
  int4 Ba1 = *(const int4*)hp1;
  uint32 wa0 = mr0[0], wa1 = mr1[0], wa2 = mr2[0], wa3 = mr3[0];
  f32x4 da0 = *(const f32x4*)(sdh + sh);
  f32x4 da1 = *(const f32x4*)(sdh + sh + 4);

  #pragma unroll 1
  for (int it = 0; it < 12; it += 2) {
    // prefetch B-set for step it+1
    int kB = (it + 1) << 5;
    int4 Bb0 = *(const int4*)(hp0 + kB);
    int4 Bb1 = *(const int4*)(hp1 + kB);
    uint32 wb0 = mr0[it + 1], wb1 = mr1[it + 1], wb2 = mr2[it + 1], wb3 = mr3[it + 1];
    f32x4 db0 = *(const f32x4*)(sdh + kB + sh);
    f32x4 db1 = *(const f32x4*)(sdh + kB + sh + 4);
    __builtin_amdgcn_sched_barrier(0);
    gat_step4(wa0, wa1, wa2, wa3, sh, da0, da1, Ba0, Ba1, ss0, ss1, ss2, ss3,
              a00, a01, a10, a11, a20, a21, a30, a31, z0, z1, z2, z3);
    // prefetch A-set for step it+2 (clamped reload on last iter, harmless)
    int itn = (it + 2 < 12) ? it + 2 : 0;
    int kA = itn << 5;
    Ba0 = *(const int4*)(hp0 + kA);
    Ba1 = *(const int4*)(hp1 + kA);
    wa0 = mr0[itn]; wa1 = mr1[itn]; wa2 = mr2[itn]; wa3 = mr3[itn];
    da0 = *(const f32x4*)(sdh + kA + sh);
    da1 = *(const f32x4*)(sdh + kA + sh + 4);
    __builtin_amdgcn_sched_barrier(0);
    gat_step4(wb0, wb1, wb2, wb3, sh, db0, db1, Bb0, Bb1, ss0, ss1, ss2, ss3,
              a00, a01, a10, a11, a20, a21, a30, a31, z0, z1, z2, z3);
  }

  // z: reduce quad partials -> lanes 0-15 hold row sums per tile
  z0 += __shfl_xor(z0, 16); z0 += __shfl_xor(z0, 32);
  z1 += __shfl_xor(z1, 16); z1 += __shfl_xor(z1, 32);
  z2 += __shfl_xor(z2, 16); z2 += __shfl_xor(z2, 32);
  z3 += __shfl_xor(z3, 16); z3 += __shfl_xor(z3, 32);
  if (lane < 16) {
    float* zb = Zpart + h * N_NODES + i0 + m;
    atomicAdd(zb, z0);
    atomicAdd(zb + 16, z1);
    atomicAdd(zb + 32, z2);
    atomicAdd(zb + 48, z3);
  }
  // partials: (h, row, col) flat; D layout: col=lane&15, row=quad*4+reg
  float* pb = part + (size_t)h * (N_NODES * 32) + (size_t)i0 * 32;
  #pragma unroll
  for (int r = 0; r < 4; ++r) {
    int row = (quad << 2) + r;
    atomicAdd(&pb[row * 32 + m], a00[r]);
    atomicAdd(&pb[row * 32 + 16 + m], a01[r]);
    atomicAdd(&pb[(16 + row) * 32 + m], a10[r]);
    atomicAdd(&pb[(16 + row) * 32 + 16 + m], a11[r]);
    atomicAdd(&pb[(32 + row) * 32 + m], a20[r]);
    atomicAdd(&pb[(32 + row) * 32 + 16 + m], a21[r]);
    atomicAdd(&pb[(48 + row) * 32 + m], a30[r]);
    atomicAdd(&pb[(48 + row) * 32 + 16 + m], a31[r]);
  }
}

// K3: out = part / Z
__global__ __launch_bounds__(256) void k3_final(const float* __restrict__ part,
                                                const float* __restrict__ Zpart,
                                                float* __restrict__ out) {
  unsigned int idx4 = blockIdx.x * 256 + threadIdx.x;   // float4 index
  unsigned int h = idx4 / 49152u;
  unsigned int i = (idx4 - h * 49152u) >> 3;
  float rz = 1.0f / Zpart[h * N_NODES + i];
  f32x4 p = ((const f32x4*)part)[idx4];
  ((f32x4*)out)[idx4] = p * rz;
}

extern "C" void kernel_launch(void* const* d_in, const int* in_sizes, int n_in,
                              void* d_out, int out_size, void* d_ws, size_t ws_size,
                              hipStream_t stream) {
  const float* x = (const float*)d_in[0];
  const int* adj = (const int*)d_in[1];
  const float* W = (const float*)d_in[2];
  const float* a = (const float*)d_in[3];
  float* out = (float*)d_out;

  float* wsf = (float*)d_ws;
  unsigned short* hfT = (unsigned short*)wsf;       // 128*6144 bf16 (1.5 MB)
  float* s_src2 = wsf + 393216;                     // 4*6144
  float* s_dst2 = s_src2 + 24576;                   // 4*6144
  float* part   = s_dst2 + 24576;                   // 786432 (3 MB)
  float* Zpart  = part + 786432;                    // 4*6144
  uint32* maskw = (uint32*)(Zpart + 24576);         // 6144*192 u32 (4.7 MB)

  (void)hipMemsetAsync(part, 0, (786432 + 24576) * sizeof(float), stream);
  hipLaunchKernelGGL(k0_pack, dim3(4608), dim3(256), 0, stream, adj, maskw);
  hipLaunchKernelGGL(k1_feat, dim3(96), dim3(256), 0, stream, x, W, a, hfT, s_src2, s_dst2);
  hipLaunchKernelGGL(k2_attn, dim3(1536), dim3(256), 0, stream,
                     maskw, hfT, s_src2, s_dst2, Zpart, part);
  hipLaunchKernelGGL(k3_final, dim3(768), dim3(256), 0, stream, part, Zpart, out);
}